// Round 1
// baseline (252.259 us; speedup 1.0000x reference)
//
#include <hip/hip_runtime.h>
#include <math.h>

// SelfCorrectingPointProcess: per-row scan over T events.
//   out[n] = loglik[n] - compensator[n]
// loglik   = sum_i m_i * (mu*t_i - beta*i)
// comp     = sum_i m_i * exp(-beta*exclN_i)/mu * (exp(mu*t_i)-exp(mu*prev_t_i))
//          + exp(-beta*totalN)/mu * (exp(mu*t1)-exp(mu*last_t))
// exclN_i  = exclusive prefix-sum of mask (wave scan)
// prev_t_i = forward-fill of last masked time; since event_times is strictly
//            increasing this is an exclusive prefix-MAX of masked times,
//            seeded with t0 (wave scan).

#define T_LEN 2048
#define CHUNK 256  // 64 lanes x float4

__global__ __launch_bounds__(256) void scpp_kernel(
    const float* __restrict__ event_times,
    const float* __restrict__ input_mask,
    const float* __restrict__ t0p, const float* __restrict__ t1p,
    const float* __restrict__ mup, const float* __restrict__ betap,
    float* __restrict__ out, int n_rows)
{
    const int lane = threadIdx.x & 63;
    const int row  = blockIdx.x * 4 + (threadIdx.x >> 6);
    if (row >= n_rows) return;

    const float t0   = t0p[0];
    const float t1   = t1p[0];
    const float mu   = log1pf(expf(mup[0]));    // softplus
    const float beta = log1pf(expf(betap[0]));  // softplus

    const float* tr = event_times + (size_t)row * T_LEN;
    const float* mr = input_mask  + (size_t)row * T_LEN;

    const float NEG = -3.402823466e38f;
    float carry_cnt  = 0.f;   // masked count so far (wave-uniform)
    float carry_maxt = t0;    // last masked time so far, seeded t0 (wave-uniform)
    float ll = 0.f, comp = 0.f;

    #pragma unroll
    for (int c = 0; c < T_LEN / CHUNK; ++c) {
        const int base = c * CHUNK + lane * 4;
        const float4 tv = *(const float4*)(tr + base);
        const float4 mv = *(const float4*)(mr + base);
        float t[4] = {tv.x, tv.y, tv.z, tv.w};
        float m[4] = {mv.x, mv.y, mv.z, mv.w};

        // lane-local exclusive scans over the 4 elements
        float cnt_ex[4], mt_ex[4];
        float acc_cnt = 0.f, acc_mt = NEG;
        #pragma unroll
        for (int j = 0; j < 4; ++j) {
            cnt_ex[j] = acc_cnt;
            mt_ex[j]  = acc_mt;
            acc_cnt += m[j];
            acc_mt   = fmaxf(acc_mt, (m[j] > 0.5f) ? t[j] : NEG);
        }

        // wave inclusive scans of the lane aggregates
        float inc_cnt = acc_cnt, inc_mt = acc_mt;
        #pragma unroll
        for (int d = 1; d < 64; d <<= 1) {
            float vc = __shfl_up(inc_cnt, d, 64);
            float vm = __shfl_up(inc_mt,  d, 64);
            if (lane >= d) { inc_cnt += vc; inc_mt = fmaxf(inc_mt, vm); }
        }
        float ex_cnt = inc_cnt - acc_cnt;          // exclusive sum for this lane
        float ex_mt  = __shfl_up(inc_mt, 1, 64);   // exclusive max for this lane
        if (lane == 0) ex_mt = NEG;

        #pragma unroll
        for (int j = 0; j < 4; ++j) {
            const float exclN = carry_cnt + ex_cnt + cnt_ex[j];
            const float prevt = fmaxf(carry_maxt, fmaxf(ex_mt, mt_ex[j]));
            comp += m[j] * expf(-beta * exclN) *
                    (expf(mu * t[j]) - expf(mu * prevt));
            ll   += m[j] * (mu * t[j] - beta * (float)(base + j));
        }

        carry_cnt  += __shfl(inc_cnt, 63, 64);
        carry_maxt  = fmaxf(carry_maxt, __shfl(inc_mt, 63, 64));
    }

    // wave-wide sum reduction of ll and comp
    #pragma unroll
    for (int d = 32; d >= 1; d >>= 1) {
        ll   += __shfl_xor(ll,   d, 64);
        comp += __shfl_xor(comp, d, 64);
    }

    if (lane == 0) {
        const float tail = expf(-beta * carry_cnt) *
                           (expf(mu * t1) - expf(mu * carry_maxt));
        out[row] = ll - (comp + tail) / mu;
    }
}

extern "C" void kernel_launch(void* const* d_in, const int* in_sizes, int n_in,
                              void* d_out, int out_size, void* d_ws, size_t ws_size,
                              hipStream_t stream) {
    const float* event_times = (const float*)d_in[0];
    // d_in[1] = spatial_locations, unused by the reference
    const float* input_mask  = (const float*)d_in[2];
    const float* t0          = (const float*)d_in[3];
    const float* t1          = (const float*)d_in[4];
    const float* mu_param    = (const float*)d_in[5];
    const float* beta_param  = (const float*)d_in[6];
    float* out = (float*)d_out;

    const int n_rows = in_sizes[0] / T_LEN;  // 8192
    dim3 grid((n_rows + 3) / 4);             // 4 waves (rows) per 256-thread block
    scpp_kernel<<<grid, 256, 0, stream>>>(event_times, input_mask, t0, t1,
                                          mu_param, beta_param, out, n_rows);
}

// Round 2
// 249.444 us; speedup vs baseline: 1.0113x; 1.0113x over previous
//
#include <hip/hip_runtime.h>
#include <math.h>

// SelfCorrectingPointProcess — telescoped form.
//
// out[n] = loglik - comp
// loglik = mu*S1 - beta*S2,  S1 = sum m_i*t_i,  S2 = sum m_i*i
// comp   = [ (1-q)*S + q^Ntot*e^{mu*t1} - e^{mu*t0} ] / mu
//   where q = e^{-beta},  S = sum_i m_i * e^{mu*t_i - beta*exclN_i}
// (telescoping of sum_k q^k (E_k - E_{k-1}) + tail; removes prev_t /
//  forward-fill scan and 2 of 3 exps per element.)
//
// exclN via ballots: mask is {0,1}; per 256-elem chunk do 4 __ballot's,
// mbcnt gives the below-lane popcount (no serial shuffle scan).

#define T_LEN 2048
#define CHUNK 256  // 64 lanes x float4

__global__ __launch_bounds__(256) void scpp_kernel(
    const float* __restrict__ event_times,
    const float* __restrict__ input_mask,
    const float* __restrict__ t0p, const float* __restrict__ t1p,
    const float* __restrict__ mup, const float* __restrict__ betap,
    float* __restrict__ out, int n_rows)
{
    const int lane = threadIdx.x & 63;
    const int row  = blockIdx.x * 4 + (threadIdx.x >> 6);
    if (row >= n_rows) return;

    const float t0   = t0p[0];
    const float t1   = t1p[0];
    const float mu   = log1pf(expf(mup[0]));    // softplus
    const float beta = log1pf(expf(betap[0]));  // softplus

    const float* tr = event_times + (size_t)row * T_LEN;
    const float* mr = input_mask  + (size_t)row * T_LEN;

    float carry = 0.f;                 // wave-uniform masked count so far
    float S = 0.f, S1 = 0.f, S2 = 0.f;

    #pragma unroll
    for (int c = 0; c < T_LEN / CHUNK; ++c) {
        const int base = c * CHUNK + lane * 4;
        const float4 tv = *(const float4*)(tr + base);
        const float4 mv = *(const float4*)(mr + base);
        const float t[4] = {tv.x, tv.y, tv.z, tv.w};
        const float m[4] = {mv.x, mv.y, mv.z, mv.w};

        // exclusive masked count via ballots (no serial scan chain)
        unsigned below_i = 0, tot_i = 0;
        #pragma unroll
        for (int j = 0; j < 4; ++j) {
            const unsigned long long b = __ballot(m[j] > 0.5f);
            below_i += __builtin_amdgcn_mbcnt_hi((unsigned)(b >> 32),
                       __builtin_amdgcn_mbcnt_lo((unsigned)b, 0u));
            tot_i   += (unsigned)__popcll(b);
        }
        const float below = (float)below_i;

        float local = 0.f;
        #pragma unroll
        for (int j = 0; j < 4; ++j) {
            const float exclN = carry + below + local;       // N before elem
            const float arg   = fmaf(mu, t[j], -beta * exclN);
            S  = fmaf(m[j], __expf(arg), S);
            S1 = fmaf(m[j], t[j], S1);
            S2 = fmaf(m[j], (float)(base + j), S2);
            local += m[j];
        }
        carry += (float)tot_i;
    }

    // butterfly reductions across the wave
    #pragma unroll
    for (int d = 32; d >= 1; d >>= 1) {
        S  += __shfl_xor(S,  d, 64);
        S1 += __shfl_xor(S1, d, 64);
        S2 += __shfl_xor(S2, d, 64);
    }

    if (lane == 0) {
        const float q   = __expf(-beta);
        const float qK  = __expf(-beta * carry);   // carry = total masked count
        const float C   = (1.f - q) * S + qK * __expf(mu * t1) - __expf(mu * t0);
        out[row] = (mu * S1 - beta * S2) - C / mu;
    }
}

extern "C" void kernel_launch(void* const* d_in, const int* in_sizes, int n_in,
                              void* d_out, int out_size, void* d_ws, size_t ws_size,
                              hipStream_t stream) {
    const float* event_times = (const float*)d_in[0];
    // d_in[1] = spatial_locations, unused by the reference
    const float* input_mask  = (const float*)d_in[2];
    const float* t0          = (const float*)d_in[3];
    const float* t1          = (const float*)d_in[4];
    const float* mu_param    = (const float*)d_in[5];
    const float* beta_param  = (const float*)d_in[6];
    float* out = (float*)d_out;

    const int n_rows = in_sizes[0] / T_LEN;  // 8192
    dim3 grid((n_rows + 3) / 4);             // 4 rows (waves) per 256-thread block
    scpp_kernel<<<grid, 256, 0, stream>>>(event_times, input_mask, t0, t1,
                                          mu_param, beta_param, out, n_rows);
}